// Round 1
// baseline (326.084 us; speedup 1.0000x reference)
//
#include <hip/hip_runtime.h>
#include <stdint.h>

#define C_IN 256
#define C_MID 64
#define KOFF 9

typedef __attribute__((ext_vector_type(8))) short bf16x8;   // 8 bf16 = 4 VGPRs
typedef __attribute__((ext_vector_type(4))) short short4v;  // 8 B packed bf16x4
typedef __attribute__((ext_vector_type(4))) float f32x4;    // MFMA C/D
typedef __attribute__((ext_vector_type(4))) float float4v;

// fp32 -> bf16 round-to-nearest-even
__device__ inline unsigned short f2bf(float f) {
    union { float f; unsigned u; } x; x.f = f;
    unsigned r = x.u + 0x7FFFu + ((x.u >> 16) & 1u);
    return (unsigned short)(r >> 16);
}

// ---------------------------------------------------------------------------
// prep (unchanged):
//   w1t[n][k] = bf16(w1[k][n] * s1[n])          [64][256]   16384 shorts
//   w2t[k][d][c] = bf16(w2[k][c][d] * s2[d])    [9][64][64] 36864 shorts
//   w3t[e][c] = bf16(w3[c][e] * s3[e])          [256][64]   16384 shorts
// ---------------------------------------------------------------------------
__global__ void prep_kernel(const float* __restrict__ w1, const float* __restrict__ s1,
                            const float* __restrict__ w2, const float* __restrict__ s2,
                            const float* __restrict__ w3, const float* __restrict__ s3,
                            unsigned short* __restrict__ w1t,
                            unsigned short* __restrict__ w2t,
                            unsigned short* __restrict__ w3t,
                            unsigned short* __restrict__ zrow) {
    int tid = blockIdx.x * blockDim.x + threadIdx.x;
    int stride = gridDim.x * blockDim.x;
    for (int i = tid; i < C_MID * C_IN; i += stride) {
        int n = i / C_IN, k = i % C_IN;
        w1t[i] = f2bf(w1[k * C_MID + n] * s1[n]);
    }
    for (int i = tid; i < KOFF * C_MID * C_MID; i += stride) {
        int k = i / (C_MID * C_MID);
        int r = i % (C_MID * C_MID);
        int d = r / C_MID, c = r % C_MID;
        w2t[i] = f2bf(w2[(k * C_MID + c) * C_MID + d] * s2[d]);
    }
    for (int i = tid; i < C_IN * C_MID; i += stride) {
        int e = i / C_MID, c = i % C_MID;
        w3t[i] = f2bf(w3[c * C_IN + e] * s3[e]);
    }
    for (int i = tid; i < C_MID; i += stride) zrow[i] = 0;
}

// ---------------------------------------------------------------------------
// conv1 v5: no LDS at all. w1 fragments read directly from global (w1t is
// 32 KB, L2-resident, every block reads the same data). Zero barriers: the
// 16 pinned feat loads flow freely; compiler inserts per-use vmcnt waits.
// Regs ~ fr 64 + acc 16 + window ~ 110 -> 4 waves/SIMD at (256,4).
// ---------------------------------------------------------------------------
__global__ __launch_bounds__(256, 4) void conv1_kernel(
    const float* __restrict__ feat, const unsigned short* __restrict__ w1t,
    const float* __restrict__ b1, unsigned short* __restrict__ out1, int N)
{
    int t = threadIdx.x;
    int wave = t >> 6;
    int lane = t & 63;
    int l15 = lane & 15;
    int quad = lane >> 4;
    int site = blockIdx.x * 64 + wave * 16 + l15;
    int sitec = site < N ? site : (N - 1);

    const bf16x8* w1c = reinterpret_cast<const bf16x8*>(w1t);

    // ---- pin all 16 feat loads (64 regs), deep in flight ----
    float4v fr[16];
#pragma unroll
    for (int kk = 0; kk < 8; ++kk) {
        const float4v* p = reinterpret_cast<const float4v*>(
            feat + (size_t)sitec * C_IN + kk * 32 + quad * 8);
        fr[kk * 2] = p[0];
        fr[kk * 2 + 1] = p[1];
    }
    __builtin_amdgcn_sched_barrier(0);

    f32x4 acc[4] = {};
#pragma unroll
    for (int kk = 0; kk < 8; ++kk) {
        union { unsigned short s[8]; bf16x8 v; } ua;
#pragma unroll
        for (int j = 0; j < 4; ++j) {
            ua.s[j] = f2bf(fr[kk * 2][j]);
            ua.s[4 + j] = f2bf(fr[kk * 2 + 1][j]);
        }
#pragma unroll
        for (int ct = 0; ct < 4; ++ct) {
            bf16x8 fa = w1c[(ct * 16 + l15) * 32 + kk * 4 + quad];
            acc[ct] = __builtin_amdgcn_mfma_f32_16x16x32_bf16(fa, ua.v, acc[ct], 0, 0, 0);
        }
    }
    if (site < N) {
#pragma unroll
        for (int ct = 0; ct < 4; ++ct) {
            float4v bb = *reinterpret_cast<const float4v*>(b1 + ct * 16 + quad * 4);
            union { unsigned short s[4]; short4v v; } o;
#pragma unroll
            for (int reg = 0; reg < 4; ++reg)
                o.s[reg] = f2bf(fmaxf(acc[ct][reg] + bb[reg], 0.f));
            *reinterpret_cast<short4v*>(out1 + (size_t)site * C_MID + ct * 16 + quad * 4) = o.v;
        }
    }
}

// ---------------------------------------------------------------------------
// conv23 v5: NO weight staging. w2t (72 KB) and w3t (32 KB) fragments are
// read directly from global — L2-resident by construction, per-instruction
// footprint = 4 x 256 B contiguous segments. LDS keeps only the mid
// transpose buffer (pitch 72 -> 2-way bank alias, free) and the staged
// rulebook. 2 barriers instead of 5; no vmcnt(0) staging drains.
// conv3 accumulator chunked (4 x 64 output channels) so rf[16] (64 regs)
// + acc3[4] (16) fits 4 waves/SIMD under (256,4).
// ---------------------------------------------------------------------------
__global__ __launch_bounds__(256, 4) void conv23_kernel(
    const float* __restrict__ feat, const int* __restrict__ nbr,
    const unsigned short* __restrict__ out1, const unsigned short* __restrict__ w2t,
    const float* __restrict__ b2, const unsigned short* __restrict__ w3t,
    const float* __restrict__ b3, float* __restrict__ out, int N)
{
    __shared__ __align__(16) unsigned short mid[64 * 72];   // 9216 B
    __shared__ int sNbr[64 * KOFF];                          // 2304 B

    int t = threadIdx.x;
    int wave = t >> 6;
    int lane = t & 63;
    int l15 = lane & 15;
    int quad = lane >> 4;
    int rt = wave * 16 + l15;
    int site = blockIdx.x * 64 + rt;
    int sitec = site < N ? site : (N - 1);

    // ---- stage rulebook (coalesced) ----
#pragma unroll
    for (int i = 0; i < 3; ++i) {
        int j = i * 256 + t;
        if (j < 64 * KOFF) {
            int g = blockIdx.x * 64 * KOFF + j;
            sNbr[j] = (g < N * KOFF) ? nbr[g] : N;
        }
    }
    __syncthreads();                                         // B1

    int nb[KOFF];
#pragma unroll
    for (int k = 0; k < KOFF; ++k) nb[k] = sNbr[rt * KOFF + k];

    // ---- pin all 18 gathers (72 regs), deep in flight ----
    bf16x8 ga[KOFF][2];
#pragma unroll
    for (int k = 0; k < KOFF; ++k) {
        const bf16x8* pg = reinterpret_cast<const bf16x8*>(out1 + (size_t)nb[k] * C_MID + quad * 8);
        ga[k][0] = pg[0];
        ga[k][1] = pg[4];
    }
    __builtin_amdgcn_sched_barrier(0);

    // ---- conv2: 72 MFMAs, A-fragments streamed from L2 ----
    const bf16x8* w2c = reinterpret_cast<const bf16x8*>(w2t);
    f32x4 acc2[4] = {};
#pragma unroll
    for (int k = 0; k < KOFF; ++k) {
#pragma unroll
        for (int kk = 0; kk < 2; ++kk) {
#pragma unroll
            for (int ct = 0; ct < 4; ++ct) {
                bf16x8 fa = w2c[k * 512 + (ct * 16 + l15) * 8 + kk * 4 + quad];
                acc2[ct] = __builtin_amdgcn_mfma_f32_16x16x32_bf16(fa, ga[k][kk], acc2[ct], 0, 0, 0);
            }
        }
    }

    // ---- bn2+relu -> mid (LDS transpose, pitch 72) ----
#pragma unroll
    for (int ct = 0; ct < 4; ++ct) {
        float4v bb = *reinterpret_cast<const float4v*>(b2 + ct * 16 + quad * 4);
        union { unsigned short s[4]; short4v v; } o;
#pragma unroll
        for (int reg = 0; reg < 4; ++reg)
            o.s[reg] = f2bf(fmaxf(acc2[ct][reg] + bb[reg], 0.f));
        *reinterpret_cast<short4v*>(&mid[rt * 72 + ct * 16 + quad * 4]) = o.v;
    }
    __syncthreads();                                         // B2 (mid RAW)

    // ---- pin 16 residual loads (drain under conv3 MFMAs) ----
    float4v rf[16];
#pragma unroll
    for (int c2 = 0; c2 < 16; ++c2)
        rf[c2] = *reinterpret_cast<const float4v*>(
            feat + (size_t)sitec * C_IN + c2 * 16 + quad * 4);
    __builtin_amdgcn_sched_barrier(0);

    // ---- conv3 chunked: 4 chunks x 64 output channels ----
    const bf16x8* w3c = reinterpret_cast<const bf16x8*>(w3t);
#pragma unroll
    for (int c = 0; c < 4; ++c) {
        f32x4 acc3[4] = {};
#pragma unroll
        for (int kk = 0; kk < 2; ++kk) {
            bf16x8 fb = *reinterpret_cast<const bf16x8*>(
                &mid[rt * 72 + kk * 32 + quad * 8]);
#pragma unroll
            for (int c2l = 0; c2l < 4; ++c2l) {
                int c2 = c * 4 + c2l;
                bf16x8 fa = w3c[(c2 * 16 + l15) * 8 + kk * 4 + quad];
                acc3[c2l] = __builtin_amdgcn_mfma_f32_16x16x32_bf16(fa, fb, acc3[c2l], 0, 0, 0);
            }
        }
        if (site < N) {
#pragma unroll
            for (int c2l = 0; c2l < 4; ++c2l) {
                int c2 = c * 4 + c2l;
                float4v bb = *reinterpret_cast<const float4v*>(b3 + c2 * 16 + quad * 4);
                float4v o;
#pragma unroll
                for (int reg = 0; reg < 4; ++reg)
                    o[reg] = fmaxf(acc3[c2l][reg] + bb[reg] + rf[c2][reg], 0.f);
                *reinterpret_cast<float4v*>(out + (size_t)site * C_IN + c2 * 16 + quad * 4) = o;
            }
        }
    }
}

extern "C" void kernel_launch(void* const* d_in, const int* in_sizes, int n_in,
                              void* d_out, int out_size, void* d_ws, size_t ws_size,
                              hipStream_t stream) {
    const float* feat = (const float*)d_in[0];
    const int*   nbr  = (const int*)d_in[1];
    const float* w1   = (const float*)d_in[2];
    const float* s1   = (const float*)d_in[3];
    const float* b1   = (const float*)d_in[4];
    const float* w2   = (const float*)d_in[5];
    const float* s2   = (const float*)d_in[6];
    const float* b2   = (const float*)d_in[7];
    const float* w3   = (const float*)d_in[8];
    const float* s3   = (const float*)d_in[9];
    const float* b3   = (const float*)d_in[10];
    float* out = (float*)d_out;
    int N = in_sizes[0] / C_IN;

    char* ws = (char*)d_ws;
    unsigned short* w1t  = (unsigned short*)(ws);                    // 32768 B
    unsigned short* w2t  = (unsigned short*)(ws + 32768);            // 73728 B
    unsigned short* w3t  = (unsigned short*)(ws + 32768 + 73728);    // 32768 B
    unsigned short* out1 = (unsigned short*)(ws + 139264);           // (N+1)*64*2 B

    prep_kernel<<<80, 256, 0, stream>>>(w1, s1, w2, s2, w3, s3, w1t, w2t, w3t,
                                        out1 + (size_t)N * C_MID);
    int nblk = (N + 63) / 64;
    conv1_kernel<<<nblk, 256, 0, stream>>>(feat, w1t, b1, out1, N);
    conv23_kernel<<<nblk, 256, 0, stream>>>(feat, nbr, out1, w2t, b2, w3t, b3, out, N);
}

// Round 4
// 266.729 us; speedup vs baseline: 1.2225x; 1.2225x over previous
//
#include <hip/hip_runtime.h>
#include <stdint.h>

#define C_IN 256
#define C_MID 64
#define KOFF 9

typedef __attribute__((ext_vector_type(8))) short bf16x8;   // 8 bf16 = 4 VGPRs
typedef __attribute__((ext_vector_type(4))) short short4v;  // 8 B packed bf16x4
typedef __attribute__((ext_vector_type(4))) float f32x4;    // MFMA C/D
typedef __attribute__((ext_vector_type(4))) float float4v;

// fp32 -> bf16 round-to-nearest-even
__device__ inline unsigned short f2bf(float f) {
    union { float f; unsigned u; } x; x.f = f;
    unsigned r = x.u + 0x7FFFu + ((x.u >> 16) & 1u);
    return (unsigned short)(r >> 16);
}

// ---------------------------------------------------------------------------
// prep (unchanged):
//   w1t[n][k] = bf16(w1[k][n] * s1[n])          [64][256]   16384 shorts
//   w2t[k][d][c] = bf16(w2[k][c][d] * s2[d])    [9][64][64] 36864 shorts
//   w3t[e][c] = bf16(w3[c][e] * s3[e])          [256][64]   16384 shorts
// ---------------------------------------------------------------------------
__global__ void prep_kernel(const float* __restrict__ w1, const float* __restrict__ s1,
                            const float* __restrict__ w2, const float* __restrict__ s2,
                            const float* __restrict__ w3, const float* __restrict__ s3,
                            unsigned short* __restrict__ w1t,
                            unsigned short* __restrict__ w2t,
                            unsigned short* __restrict__ w3t,
                            unsigned short* __restrict__ zrow) {
    int tid = blockIdx.x * blockDim.x + threadIdx.x;
    int stride = gridDim.x * blockDim.x;
    for (int i = tid; i < C_MID * C_IN; i += stride) {
        int n = i / C_IN, k = i % C_IN;
        w1t[i] = f2bf(w1[k * C_MID + n] * s1[n]);
    }
    for (int i = tid; i < KOFF * C_MID * C_MID; i += stride) {
        int k = i / (C_MID * C_MID);
        int r = i % (C_MID * C_MID);
        int d = r / C_MID, c = r % C_MID;
        w2t[i] = f2bf(w2[(k * C_MID + c) * C_MID + d] * s2[d]);
    }
    for (int i = tid; i < C_IN * C_MID; i += stride) {
        int e = i / C_MID, c = i % C_MID;
        w3t[i] = f2bf(w3[c * C_IN + e] * s3[e]);
    }
    for (int i = tid; i < C_MID; i += stride) zrow[i] = 0;
}

// ---------------------------------------------------------------------------
// conv1 v4 (R0 verbatim — part of the 260.7 µs baseline): role-swapped,
// LDS = sW1 only (32.8 KB -> 4 blocks/CU). fr loads split into two pinned
// groups of 8 float4 (peak ~95 regs <= 128 cap, no spill).
// ---------------------------------------------------------------------------
__global__ __launch_bounds__(256, 4) void conv1_kernel(
    const float* __restrict__ feat, const unsigned short* __restrict__ w1t,
    const float* __restrict__ b1, unsigned short* __restrict__ out1, int N)
{
    __shared__ __align__(16) unsigned short sW1[16384];      // 32768 B

    int t = threadIdx.x;
    int wave = t >> 6;
    int lane = t & 63;
    int l15 = lane & 15;
    int quad = lane >> 4;
    int site = blockIdx.x * 64 + wave * 16 + l15;
    int sitec = site < N ? site : (N - 1);

    const bf16x8* w1c = reinterpret_cast<const bf16x8*>(w1t);
    bf16x8* sW1c = reinterpret_cast<bf16x8*>(sW1);
#pragma unroll
    for (int it = 0; it < 8; ++it) {
        int s = it * 256 + t;
        int l = s & 15, ct = (s >> 4) & 3, q = (s >> 6) & 3, kk = s >> 8;
        sW1c[s] = w1c[(ct * 16 + l) * 32 + kk * 4 + q];
    }

    // ---- pin group 0: kk = 0..3 (8 float4 = 32 regs) ----
    float4v fr0[8];
#pragma unroll
    for (int kk = 0; kk < 4; ++kk) {
        const float4v* p = reinterpret_cast<const float4v*>(
            feat + (size_t)sitec * C_IN + kk * 32 + quad * 8);
        fr0[kk * 2] = p[0];
        fr0[kk * 2 + 1] = p[1];
    }
    __builtin_amdgcn_sched_barrier(0);
    __syncthreads();

    // ---- pin group 1: kk = 4..7 (in flight during group-0 compute) ----
    float4v fr1[8];
#pragma unroll
    for (int kk = 0; kk < 4; ++kk) {
        const float4v* p = reinterpret_cast<const float4v*>(
            feat + (size_t)sitec * C_IN + (kk + 4) * 32 + quad * 8);
        fr1[kk * 2] = p[0];
        fr1[kk * 2 + 1] = p[1];
    }
    __builtin_amdgcn_sched_barrier(0);

    f32x4 acc[4] = {};
#pragma unroll
    for (int kk = 0; kk < 4; ++kk) {
        union { unsigned short s[8]; bf16x8 v; } ua;
#pragma unroll
        for (int j = 0; j < 4; ++j) {
            ua.s[j] = f2bf(fr0[kk * 2][j]);
            ua.s[4 + j] = f2bf(fr0[kk * 2 + 1][j]);
        }
#pragma unroll
        for (int ct = 0; ct < 4; ++ct) {
            bf16x8 fa = sW1c[((kk * 4 + quad) * 4 + ct) * 16 + l15];
            acc[ct] = __builtin_amdgcn_mfma_f32_16x16x32_bf16(fa, ua.v, acc[ct], 0, 0, 0);
        }
    }
#pragma unroll
    for (int kk = 0; kk < 4; ++kk) {
        union { unsigned short s[8]; bf16x8 v; } ua;
#pragma unroll
        for (int j = 0; j < 4; ++j) {
            ua.s[j] = f2bf(fr1[kk * 2][j]);
            ua.s[4 + j] = f2bf(fr1[kk * 2 + 1][j]);
        }
#pragma unroll
        for (int ct = 0; ct < 4; ++ct) {
            bf16x8 fa = sW1c[(((kk + 4) * 4 + quad) * 4 + ct) * 16 + l15];
            acc[ct] = __builtin_amdgcn_mfma_f32_16x16x32_bf16(fa, ua.v, acc[ct], 0, 0, 0);
        }
    }
    if (site < N) {
#pragma unroll
        for (int ct = 0; ct < 4; ++ct) {
            float4v bb = *reinterpret_cast<const float4v*>(b1 + ct * 16 + quad * 4);
            union { unsigned short s[4]; short4v v; } o;
#pragma unroll
            for (int reg = 0; reg < 4; ++reg)
                o.s[reg] = f2bf(fmaxf(acc[ct][reg] + bb[reg], 0.f));
            *reinterpret_cast<short4v*>(out1 + (size_t)site * C_MID + ct * 16 + quad * 4) = o.v;
        }
    }
}

// ---------------------------------------------------------------------------
// conv2 v7: gather + 72 MFMAs + bn/relu -> mid (global bf16). w2 staged in
// 3 phases of 3 k-offsets (24576 B) + nbr (2304 B) = 26880 B LDS. (256,3):
// VGPR cap ~170, peak live ~130 (ga 72 + staging 24 + acc 16 + misc).
// ---------------------------------------------------------------------------
__global__ __launch_bounds__(256, 3) void conv2_kernel(
    const int* __restrict__ nbr, const unsigned short* __restrict__ out1,
    const unsigned short* __restrict__ w2t, const float* __restrict__ b2,
    unsigned short* __restrict__ mid, int N)
{
    __shared__ __align__(16) unsigned short sW2[12288];      // 24576 B
    __shared__ int sNbr[64 * KOFF];                          // 2304 B

    int t = threadIdx.x;
    int wave = t >> 6;
    int lane = t & 63;
    int l15 = lane & 15;
    int quad = lane >> 4;
    int rt = wave * 16 + l15;
    int site = blockIdx.x * 64 + rt;

    bf16x8* sW2c = reinterpret_cast<bf16x8*>(sW2);
    const bf16x8* w2c = reinterpret_cast<const bf16x8*>(w2t);

    // ---- stage w2 phase0 (k=0..2, 1536 chunks, 6/thread) + rulebook ----
#pragma unroll
    for (int it = 0; it < 6; ++it) {
        int s = it * 256 + t;
        int l = s & 15, ct = (s >> 4) & 3, q = (s >> 6) & 3, kk = (s >> 8) & 1, k2 = s >> 9;
        sW2c[s] = w2c[k2 * 512 + (ct * 16 + l) * 8 + kk * 4 + q];
    }
#pragma unroll
    for (int i = 0; i < 3; ++i) {
        int j = i * 256 + t;
        if (j < 64 * KOFF) {
            int g = blockIdx.x * 64 * KOFF + j;
            sNbr[j] = (g < N * KOFF) ? nbr[g] : N;
        }
    }
    __syncthreads();                                         // B1

    int nb[KOFF];
#pragma unroll
    for (int k = 0; k < KOFF; ++k) nb[k] = sNbr[rt * KOFF + k];

    // ---- pin all 18 gathers (72 regs), deep in flight ----
    bf16x8 ga[KOFF][2];
#pragma unroll
    for (int k = 0; k < KOFF; ++k) {
        const bf16x8* pg = reinterpret_cast<const bf16x8*>(out1 + (size_t)nb[k] * C_MID + quad * 8);
        ga[k][0] = pg[0];
        ga[k][1] = pg[4];
    }
    __builtin_amdgcn_sched_barrier(0);

    f32x4 acc2[4] = {};
    // ---- phase 0: k=0..2 ----
#pragma unroll
    for (int k2 = 0; k2 < 3; ++k2) {
#pragma unroll
        for (int kk = 0; kk < 2; ++kk) {
#pragma unroll
            for (int ct = 0; ct < 4; ++ct) {
                bf16x8 fa = sW2c[((k2 * 2 + kk) * 4 + quad) * 64 + ct * 16 + l15];
                acc2[ct] = __builtin_amdgcn_mfma_f32_16x16x32_bf16(fa, ga[k2][kk], acc2[ct], 0, 0, 0);
            }
        }
    }
    __syncthreads();                                         // B2: phase0 reads done

    // ---- stage w2 phase1 (k=3..5) ----
#pragma unroll
    for (int it = 0; it < 6; ++it) {
        int s = it * 256 + t;
        int l = s & 15, ct = (s >> 4) & 3, q = (s >> 6) & 3, kk = (s >> 8) & 1, k2 = s >> 9;
        sW2c[s] = w2c[(3 + k2) * 512 + (ct * 16 + l) * 8 + kk * 4 + q];
    }
    __syncthreads();                                         // B3
#pragma unroll
    for (int k2 = 0; k2 < 3; ++k2) {
#pragma unroll
        for (int kk = 0; kk < 2; ++kk) {
#pragma unroll
            for (int ct = 0; ct < 4; ++ct) {
                bf16x8 fa = sW2c[((k2 * 2 + kk) * 4 + quad) * 64 + ct * 16 + l15];
                acc2[ct] = __builtin_amdgcn_mfma_f32_16x16x32_bf16(fa, ga[3 + k2][kk], acc2[ct], 0, 0, 0);
            }
        }
    }
    __syncthreads();                                         // B4: phase1 reads done

    // ---- stage w2 phase2 (k=6..8) ----
#pragma unroll
    for (int it = 0; it < 6; ++it) {
        int s = it * 256 + t;
        int l = s & 15, ct = (s >> 4) & 3, q = (s >> 6) & 3, kk = (s >> 8) & 1, k2 = s >> 9;
        sW2c[s] = w2c[(6 + k2) * 512 + (ct * 16 + l) * 8 + kk * 4 + q];
    }
    __syncthreads();                                         // B5
#pragma unroll
    for (int k2 = 0; k2 < 3; ++k2) {
#pragma unroll
        for (int kk = 0; kk < 2; ++kk) {
#pragma unroll
            for (int ct = 0; ct < 4; ++ct) {
                bf16x8 fa = sW2c[((k2 * 2 + kk) * 4 + quad) * 64 + ct * 16 + l15];
                acc2[ct] = __builtin_amdgcn_mfma_f32_16x16x32_bf16(fa, ga[6 + k2][kk], acc2[ct], 0, 0, 0);
            }
        }
    }

    // ---- bn2 + relu -> mid (global bf16, plain [site][64] layout) ----
    if (site < N) {
#pragma unroll
        for (int ct = 0; ct < 4; ++ct) {
            float4v bb = *reinterpret_cast<const float4v*>(b2 + ct * 16 + quad * 4);
            union { unsigned short s[4]; short4v v; } o;
#pragma unroll
            for (int reg = 0; reg < 4; ++reg)
                o.s[reg] = f2bf(fmaxf(acc2[ct][reg] + bb[reg], 0.f));
            *reinterpret_cast<short4v*>(mid + (size_t)site * C_MID + ct * 16 + quad * 4) = o.v;
        }
    }
}

// ---------------------------------------------------------------------------
// conv3 v7: pure streaming kernel, ONE barrier. Stage w3 (32 KB LDS); while
// staging is in flight, pin fb (mid row — conv2->conv3 re-layout is free via
// global addressing) and rf (residual). acc3 chunked 4x4 (16 regs).
// (256,3): cap ~170, peak live ~130.
// ---------------------------------------------------------------------------
__global__ __launch_bounds__(256, 3) void conv3_kernel(
    const float* __restrict__ feat, const unsigned short* __restrict__ mid,
    const unsigned short* __restrict__ w3t, const float* __restrict__ b3,
    float* __restrict__ out, int N)
{
    __shared__ __align__(16) unsigned short sW3[16384];      // 32768 B

    int t = threadIdx.x;
    int wave = t >> 6;
    int lane = t & 63;
    int l15 = lane & 15;
    int quad = lane >> 4;
    int site = blockIdx.x * 64 + wave * 16 + l15;
    int sitec = site < N ? site : (N - 1);

    bf16x8* sW3c = reinterpret_cast<bf16x8*>(sW3);
    const bf16x8* w3c = reinterpret_cast<const bf16x8*>(w3t);
#pragma unroll
    for (int it = 0; it < 8; ++it) {
        int s = it * 256 + t;
        int l = s & 15, c2 = (s >> 4) & 15, q = (s >> 8) & 3, kk = (s >> 10) & 1;
        sW3c[s] = w3c[(c2 * 16 + l) * 8 + kk * 4 + q];
    }

    // ---- pin fb (mid row halves) + rf (residual) under the staging ----
    bf16x8 fb0 = *reinterpret_cast<const bf16x8*>(mid + (size_t)sitec * C_MID + quad * 8);
    bf16x8 fb1 = *reinterpret_cast<const bf16x8*>(mid + (size_t)sitec * C_MID + 32 + quad * 8);
    float4v rf[16];
#pragma unroll
    for (int c2 = 0; c2 < 16; ++c2)
        rf[c2] = *reinterpret_cast<const float4v*>(
            feat + (size_t)sitec * C_IN + c2 * 16 + quad * 4);
    __builtin_amdgcn_sched_barrier(0);
    __syncthreads();                                         // B1 (only barrier)

#pragma unroll
    for (int c = 0; c < 4; ++c) {
        f32x4 acc3[4] = {};
#pragma unroll
        for (int c2l = 0; c2l < 4; ++c2l) {
            int c2 = c * 4 + c2l;
            bf16x8 fa0 = sW3c[((0 * 4 + quad) * 16 + c2) * 16 + l15];
            acc3[c2l] = __builtin_amdgcn_mfma_f32_16x16x32_bf16(fa0, fb0, acc3[c2l], 0, 0, 0);
            bf16x8 fa1 = sW3c[((1 * 4 + quad) * 16 + c2) * 16 + l15];
            acc3[c2l] = __builtin_amdgcn_mfma_f32_16x16x32_bf16(fa1, fb1, acc3[c2l], 0, 0, 0);
        }
        if (site < N) {
#pragma unroll
            for (int c2l = 0; c2l < 4; ++c2l) {
                int c2 = c * 4 + c2l;
                float4v bb = *reinterpret_cast<const float4v*>(b3 + c2 * 16 + quad * 4);
                float4v o;
#pragma unroll
                for (int reg = 0; reg < 4; ++reg)
                    o[reg] = fmaxf(acc3[c2l][reg] + bb[reg] + rf[c2][reg], 0.f);
                *reinterpret_cast<float4v*>(out + (size_t)site * C_IN + c2 * 16 + quad * 4) = o;
            }
        }
    }
}

// ---------------------------------------------------------------------------
// conv23 (R0 verbatim, 260.7 µs-proven) — FALLBACK when ws_size can't fit
// the split path's mid buffer.
// ---------------------------------------------------------------------------
__global__ __launch_bounds__(256, 2) void conv23_kernel(
    const float* __restrict__ feat, const int* __restrict__ nbr,
    const unsigned short* __restrict__ out1, const unsigned short* __restrict__ w2t,
    const float* __restrict__ b2, const unsigned short* __restrict__ w3t,
    const float* __restrict__ b3, float* __restrict__ out, int N)
{
    __shared__ __align__(16) unsigned short sWB[21504];      // 43008 B
    __shared__ int sNbr[64 * KOFF];                          // 2304 B

    int t = threadIdx.x;
    int wave = t >> 6;
    int lane = t & 63;
    int l15 = lane & 15;
    int quad = lane >> 4;
    int rt = wave * 16 + l15;
    int site = blockIdx.x * 64 + rt;
    int sitec = site < N ? site : (N - 1);

    bf16x8* sWBc = reinterpret_cast<bf16x8*>(sWB);
    const bf16x8* w2c = reinterpret_cast<const bf16x8*>(w2t);

#pragma unroll
    for (int it = 0; it < 10; ++it) {
        int s = it * 256 + t;
        int l = s & 15, ct = (s >> 4) & 3, q = (s >> 6) & 3, kk = (s >> 8) & 1, k = s >> 9;
        sWBc[s] = w2c[k * 512 + (ct * 16 + l) * 8 + kk * 4 + q];
    }
#pragma unroll
    for (int i = 0; i < 3; ++i) {
        int j = i * 256 + t;
        if (j < 64 * KOFF) {
            int g = blockIdx.x * 64 * KOFF + j;
            sNbr[j] = (g < N * KOFF) ? nbr[g] : N;
        }
    }
    __syncthreads();                                         // B1

    int nb[KOFF];
#pragma unroll
    for (int k = 0; k < KOFF; ++k) nb[k] = sNbr[rt * KOFF + k];

    bf16x8 ga[KOFF][2];
#pragma unroll
    for (int k = 0; k < KOFF; ++k) {
        const bf16x8* pg = reinterpret_cast<const bf16x8*>(out1 + (size_t)nb[k] * C_MID + quad * 8);
        ga[k][0] = pg[0];
        ga[k][1] = pg[4];
    }
    __builtin_amdgcn_sched_barrier(0);

    f32x4 acc2[4] = {};
#pragma unroll
    for (int k = 0; k < 5; ++k) {
#pragma unroll
        for (int kk = 0; kk < 2; ++kk) {
#pragma unroll
            for (int ct = 0; ct < 4; ++ct) {
                bf16x8 fa = sWBc[((k * 2 + kk) * 4 + quad) * 64 + ct * 16 + l15];
                acc2[ct] = __builtin_amdgcn_mfma_f32_16x16x32_bf16(fa, ga[k][kk], acc2[ct], 0, 0, 0);
            }
        }
    }
    __syncthreads();                                         // B2

#pragma unroll
    for (int it = 0; it < 8; ++it) {
        int s = it * 256 + t;
        int l = s & 15, ct = (s >> 4) & 3, q = (s >> 6) & 3, kk = (s >> 8) & 1, k2 = s >> 9;
        sWBc[s] = w2c[(5 + k2) * 512 + (ct * 16 + l) * 8 + kk * 4 + q];
    }
    __syncthreads();                                         // B3
#pragma unroll
    for (int k = 5; k < KOFF; ++k) {
        int kloc = k - 5;
#pragma unroll
        for (int kk = 0; kk < 2; ++kk) {
#pragma unroll
            for (int ct = 0; ct < 4; ++ct) {
                bf16x8 fa = sWBc[((kloc * 2 + kk) * 4 + quad) * 64 + ct * 16 + l15];
                acc2[ct] = __builtin_amdgcn_mfma_f32_16x16x32_bf16(fa, ga[k][kk], acc2[ct], 0, 0, 0);
            }
        }
    }
    float4v rf[16];
#pragma unroll
    for (int c2 = 0; c2 < 16; ++c2)
        rf[c2] = *reinterpret_cast<const float4v*>(
            feat + (size_t)sitec * C_IN + c2 * 16 + quad * 4);
    __builtin_amdgcn_sched_barrier(0);
    __syncthreads();                                         // B4

    unsigned short* midl = &sWB[16384];
#pragma unroll
    for (int ct = 0; ct < 4; ++ct) {
        float4v bb = *reinterpret_cast<const float4v*>(b2 + ct * 16 + quad * 4);
        union { unsigned short s[4]; short4v v; } o;
#pragma unroll
        for (int reg = 0; reg < 4; ++reg)
            o.s[reg] = f2bf(fmaxf(acc2[ct][reg] + bb[reg], 0.f));
        *reinterpret_cast<short4v*>(&midl[rt * 72 + ct * 16 + quad * 4]) = o.v;
    }
    const bf16x8* w3c = reinterpret_cast<const bf16x8*>(w3t);
#pragma unroll
    for (int it = 0; it < 8; ++it) {
        int s = it * 256 + t;
        int l = s & 15, c2 = (s >> 4) & 15, q = (s >> 8) & 3, kk = (s >> 10) & 1;
        sWBc[s] = w3c[(c2 * 16 + l) * 8 + kk * 4 + q];
    }
    __syncthreads();                                         // B5

    f32x4 acc3[16] = {};
#pragma unroll
    for (int kk = 0; kk < 2; ++kk) {
        bf16x8 fb = *reinterpret_cast<const bf16x8*>(
            &midl[rt * 72 + kk * 32 + quad * 8]);
#pragma unroll
        for (int c2 = 0; c2 < 16; ++c2) {
            bf16x8 fa = sWBc[((kk * 4 + quad) * 16 + c2) * 16 + l15];
            acc3[c2] = __builtin_amdgcn_mfma_f32_16x16x32_bf16(fa, fb, acc3[c2], 0, 0, 0);
        }
    }
    if (site < N) {
#pragma unroll
        for (int c2 = 0; c2 < 16; ++c2) {
            float4v bb = *reinterpret_cast<const float4v*>(b3 + c2 * 16 + quad * 4);
            float4v o;
#pragma unroll
            for (int reg = 0; reg < 4; ++reg)
                o[reg] = fmaxf(acc3[c2][reg] + bb[reg] + rf[c2][reg], 0.f);
            *reinterpret_cast<float4v*>(out + (size_t)site * C_IN + c2 * 16 + quad * 4) = o;
        }
    }
}

extern "C" void kernel_launch(void* const* d_in, const int* in_sizes, int n_in,
                              void* d_out, int out_size, void* d_ws, size_t ws_size,
                              hipStream_t stream) {
    const float* feat = (const float*)d_in[0];
    const int*   nbr  = (const int*)d_in[1];
    const float* w1   = (const float*)d_in[2];
    const float* s1   = (const float*)d_in[3];
    const float* b1   = (const float*)d_in[4];
    const float* w2   = (const float*)d_in[5];
    const float* s2   = (const float*)d_in[6];
    const float* b2   = (const float*)d_in[7];
    const float* w3   = (const float*)d_in[8];
    const float* s3   = (const float*)d_in[9];
    const float* b3   = (const float*)d_in[10];
    float* out = (float*)d_out;
    int N = in_sizes[0] / C_IN;

    char* ws = (char*)d_ws;
    unsigned short* w1t  = (unsigned short*)(ws);                    // 32768 B
    unsigned short* w2t  = (unsigned short*)(ws + 32768);            // 73728 B
    unsigned short* w3t  = (unsigned short*)(ws + 32768 + 73728);    // 32768 B
    unsigned short* out1 = (unsigned short*)(ws + 139264);           // (N+1)*64*2 B

    size_t out1_bytes = (size_t)(N + 1) * C_MID * 2;
    size_t need_split = 139264 + out1_bytes + (size_t)N * C_MID * 2;

    prep_kernel<<<80, 256, 0, stream>>>(w1, s1, w2, s2, w3, s3, w1t, w2t, w3t,
                                        out1 + (size_t)N * C_MID);
    int nblk = (N + 63) / 64;
    conv1_kernel<<<nblk, 256, 0, stream>>>(feat, w1t, b1, out1, N);

    if (ws_size >= need_split) {
        unsigned short* mid = (unsigned short*)(ws + 139264 + out1_bytes);
        conv2_kernel<<<nblk, 256, 0, stream>>>(nbr, out1, w2t, b2, mid, N);
        conv3_kernel<<<nblk, 256, 0, stream>>>(feat, mid, w3t, b3, out, N);
    } else {
        conv23_kernel<<<nblk, 256, 0, stream>>>(feat, nbr, out1, w2t, b2, w3t, b3, out, N);
    }
}